// Round 8
// baseline (720.856 us; speedup 1.0000x reference)
//
#include <hip/hip_runtime.h>
#include <hip/hip_bf16.h>
#include <stdint.h>

#define DIM 128
#define NNODE 100000

typedef __attribute__((ext_vector_type(8))) short short8;
typedef __attribute__((ext_vector_type(4))) float f32x4;

__device__ __forceinline__ unsigned short f32_to_bf16_rne(float f) {
    union { float f; uint32_t u; } v; v.f = f;
    uint32_t u = v.u;
    uint32_t r = u + 0x7FFFu + ((u >> 16) & 1u);
    return (unsigned short)(r >> 16);
}
__device__ __forceinline__ float bf16_to_f32(unsigned short u) {
    union { uint32_t i; float f; } v; v.i = ((uint32_t)u) << 16; return v.f;
}

// ================= counting sort (global atomics; deg~10 over 300K counters) =========
__global__ __launch_bounds__(256) void edge_hist(
    const int* __restrict__ ei0, const int* __restrict__ ei1, const int* __restrict__ ei2,
    int E0, int E1, int E2, int* __restrict__ deg) {
    int Etot = E0 + E1 + E2;
    for (int e = blockIdx.x * 256 + threadIdx.x; e < Etot; e += gridDim.x * 256) {
        int rel, le; const int* ei; int E;
        if (e < E0)           { rel = 0; le = e;           ei = ei0; E = E0; }
        else if (e < E0 + E1) { rel = 1; le = e - E0;      ei = ei1; E = E1; }
        else                  { rel = 2; le = e - E0 - E1; ei = ei2; E = E2; }
        atomicAdd(&deg[rel * NNODE + ei[E + le]], 1);
    }
}

// scan stage A: per-1024 block exclusive scan + block sums
__global__ __launch_bounds__(1024) void scan_a(const int* __restrict__ deg,
                                               int* __restrict__ loc,
                                               int* __restrict__ bsum, int n) {
    __shared__ int s[1024];
    int t = threadIdx.x;
    int gid = blockIdx.x * 1024 + t;
    int v = (gid < n) ? deg[gid] : 0;
    s[t] = v;
    __syncthreads();
    for (int d = 1; d < 1024; d <<= 1) {
        int x = (t >= d) ? s[t - d] : 0;
        __syncthreads();
        s[t] += x;
        __syncthreads();
    }
    if (gid < n) loc[gid] = s[t] - v;        // local exclusive prefix
    if (t == 1023) bsum[blockIdx.x] = s[1023];
}

// scan stage B: exclusive scan of block sums (nb <= 512), 1 block
__global__ __launch_bounds__(512) void scan_b(int* __restrict__ bsum, int nb) {
    __shared__ int s[512];
    int t = threadIdx.x;
    int v = (t < nb) ? bsum[t] : 0;
    s[t] = v;
    __syncthreads();
    for (int d = 1; d < 512; d <<= 1) {
        int x = (t >= d) ? s[t - d] : 0;
        __syncthreads();
        s[t] += x;
        __syncthreads();
    }
    if (t < nb) bsum[t] = s[t] - v;          // exclusive block offsets
}

// scan stage C: final CSR offsets + scatter cursors
__global__ __launch_bounds__(256) void scan_c(const int* __restrict__ loc,
                                              const int* __restrict__ bsum,
                                              int* __restrict__ off, int* __restrict__ cursor,
                                              int n, int Etot) {
    int i = blockIdx.x * 256 + threadIdx.x;
    if (i < n) {
        int o = loc[i] + bsum[i >> 10];
        off[i] = o; cursor[i] = o;
    }
    if (i == n) off[n] = Etot;
}

__global__ __launch_bounds__(256) void edge_scatter(
    const int* __restrict__ ei0, const int* __restrict__ ei1, const int* __restrict__ ei2,
    int E0, int E1, int E2, int* __restrict__ cursor, int* __restrict__ sorted) {
    int Etot = E0 + E1 + E2;
    for (int e = blockIdx.x * 256 + threadIdx.x; e < Etot; e += gridDim.x * 256) {
        int rel, le; const int* ei; int E;
        if (e < E0)           { rel = 0; le = e;           ei = ei0; E = E0; }
        else if (e < E0 + E1) { rel = 1; le = e - E0;      ei = ei1; E = E1; }
        else                  { rel = 2; le = e - E0 - E1; ei = ei2; E = E2; }
        int d = ei[E + le];
        int srcv = ei[le];
        int pos = atomicAdd(&cursor[rel * NNODE + d], 1);
        sorted[pos] = srcv;                  // within-dst order arbitrary (sum order only)
    }
}

// ---------------- pack weights into MFMA B-fragment order (bf16) + biases ----------------
__global__ void pack_kernel(const float* __restrict__ Wl_b, const float* __restrict__ Wr_b,
                            const float* __restrict__ b_b,
                            const float* __restrict__ Wl_r, const float* __restrict__ Wr_r,
                            const float* __restrict__ b_r,
                            const float* __restrict__ Wl_t, const float* __restrict__ Wr_t,
                            const float* __restrict__ b_t,
                            unsigned short* __restrict__ pw_item,
                            unsigned short* __restrict__ pw_user,
                            float* __restrict__ bias_item, float* __restrict__ bias_user) {
    const int NI = 12 * 8 * 64 * 8;   // item slots: [.5Wl_b | .5Wl_t | .5(Wr_b+Wr_t)]
    const int NU = 8 * 8 * 64 * 8;    // user slots: [Wl_r | Wr_r]
    int o = blockIdx.x * blockDim.x + threadIdx.x;
    if (o < NI) {
        int j = o & 7, lane = (o >> 3) & 63, ks = o >> 12;
        int n = ((o >> 9) & 7) * 16 + (lane & 15);
        int k = (ks & 3) * 32 + (lane >> 4) * 8 + j;
        int src = ks >> 2;
        float v;
        if (src == 0)      v = 0.5f * Wl_b[k * DIM + n];
        else if (src == 1) v = 0.5f * Wl_t[k * DIM + n];
        else               v = 0.5f * (Wr_b[k * DIM + n] + Wr_t[k * DIM + n]);
        pw_item[o] = f32_to_bf16_rne(v);
    } else if (o < NI + NU) {
        int oo = o - NI;
        int j = oo & 7, lane = (oo >> 3) & 63, ks = oo >> 12;
        int n = ((oo >> 9) & 7) * 16 + (lane & 15);
        int k = (ks & 3) * 32 + (lane >> 4) * 8 + j;
        float v = ((ks >> 2) == 0) ? Wl_r[k * DIM + n] : Wr_r[k * DIM + n];
        pw_user[oo] = f32_to_bf16_rne(v);
    } else {
        int oo = o - NI - NU;
        if (oo < DIM)            bias_item[oo] = 0.5f * (b_b[oo] + b_t[oo]);
        else if (oo < 2 * DIM)   bias_user[oo - DIM] = b_r[oo - DIM];
    }
}

// ================= conv + pre-GEMM: x(f32) -> y = x@Wl (bf16), r = x@Wr + b (bf16) ====
// Linearity: mean(x[srcs])@W = mean((x@W)[srcs]) — gather tables carry x@W directly,
// so the agg kernel is a pure gather. One wave per 16 rows; wave-private LDS; fragment
// patterns HW-verified (rounds 1/4/7).
__device__ __forceinline__ void cg_product(
    unsigned char* stage, const short8* af,
    const unsigned short* __restrict__ pw, int slot0,
    const float* __restrict__ bias,            // nullptr for y products
    unsigned short* __restrict__ dst, int g0, int lane) {
    const int quad = lane >> 4, l15 = lane & 15;
    f32x4 acc[8];
    #pragma unroll
    for (int i = 0; i < 8; i++) acc[i] = (f32x4){0.f, 0.f, 0.f, 0.f};
    #pragma unroll
    for (int ksl = 0; ksl < 4; ksl++) {
        const unsigned short* wp = pw + ((size_t)(slot0 + ksl) * 8 * 64 + lane) * 8;
        #pragma unroll
        for (int nt = 0; nt < 8; nt++) {
            short8 wfrag = *(const short8*)(wp + (size_t)nt * 64 * 8);
            acc[nt] = __builtin_amdgcn_mfma_f32_16x16x32_bf16(af[ksl], wfrag, acc[nt], 0, 0, 0);
        }
    }
    unsigned short* outb = (unsigned short*)stage;
    #pragma unroll
    for (int nt = 0; nt < 8; nt++) {
        float bv = bias ? bias[nt * 16 + l15] : 0.f;
        #pragma unroll
        for (int r = 0; r < 4; r++) {
            outb[(((quad << 2) + r) << 7) + (nt << 4) + l15] =
                f32_to_bf16_rne(acc[nt][r] + bv);
        }
    }
    unsigned char* mp = (unsigned char*)(dst + ((size_t)g0 << 7));
    #pragma unroll
    for (int s = 0; s < 4; s++) {
        uint4 vv = *(const uint4*)(stage + (s << 10) + (lane << 4));
        *(uint4*)(mp + (s << 10) + (lane << 4)) = vv;
    }
}

__global__ __launch_bounds__(256) void conv_gemm(
    const float* __restrict__ xu, const float* __restrict__ xi, const float* __restrict__ xt,
    const unsigned short* __restrict__ pw_item, const unsigned short* __restrict__ pw_user,
    const float* __restrict__ bias_item, const float* __restrict__ bias_user,
    unsigned short* __restrict__ yu, unsigned short* __restrict__ yi,
    unsigned short* __restrict__ yt,
    unsigned short* __restrict__ ru, unsigned short* __restrict__ ri,
    int GU, int GI, int GT) {
    __shared__ __align__(1024) unsigned char smem[4][4096];
    const int wid = threadIdx.x >> 6;
    const int lane = threadIdx.x & 63;
    const int grp = blockIdx.x * 4 + wid;
    if (grp >= GU + GI + GT) return;
    const float* src; const unsigned short *pwA, *pwB; const float* biasB;
    unsigned short *outA, *outB; int slotA, slotB, g0; bool two;
    if (grp < GU) {
        g0 = grp << 4; src = xu + ((size_t)g0 << 7);
        pwA = pw_item; slotA = 0; outA = yu;                   // yu = x_user @ .5Wl_b
        pwB = pw_user; slotB = 4; outB = ru; biasB = bias_user; two = true;  // r_user
    } else if (grp < GU + GI) {
        g0 = (grp - GU) << 4; src = xi + ((size_t)g0 << 7);
        pwA = pw_user; slotA = 0; outA = yi;                   // yi = x_item @ Wl_r
        pwB = pw_item; slotB = 8; outB = ri; biasB = bias_item; two = true;  // r_item
    } else {
        g0 = (grp - GU - GI) << 4; src = xt + ((size_t)g0 << 7);
        pwA = pw_item; slotA = 4; outA = yt; two = false;      // yt = x_tag @ .5Wl_t
        pwB = nullptr; outB = nullptr; biasB = nullptr; slotB = 0;
    }
    unsigned char* stage = smem[wid];
    // stream 16 rows (8KB f32, coalesced) -> bf16 swizzled LDS tile [16][128]
    #pragma unroll
    for (int s = 0; s < 8; s++) {
        float4 f = *(const float4*)((const unsigned char*)src + (s << 10) + (lane << 4));
        int row = (s << 1) + (lane >> 5);
        unsigned int b = ((unsigned int)row << 8) + ((unsigned int)(lane & 31) << 3);
        b ^= (unsigned int)((row & 15) << 4);
        ushort4 u;
        u.x = f32_to_bf16_rne(f.x); u.y = f32_to_bf16_rne(f.y);
        u.z = f32_to_bf16_rne(f.z); u.w = f32_to_bf16_rne(f.w);
        *(ushort4*)(stage + b) = u;
    }
    // A-fragments (row = lane&15, k = ksl*32 + quad*8 .. +8); same XOR on read
    short8 af[4];
    const int quad = lane >> 4, l15 = lane & 15;
    #pragma unroll
    for (int ksl = 0; ksl < 4; ksl++) {
        unsigned int rb = ((unsigned int)l15 << 8) + (ksl << 6) + (quad << 4);
        rb ^= (unsigned int)(l15 << 4);
        af[ksl] = *(const short8*)(stage + rb);
    }
    cg_product(stage, af, pwA, slotA, nullptr, outA, g0, lane);
    if (two) cg_product(stage, af, pwB, slotB, biasB, outB, g0, lane);
}

// ================= MFMA segment mean over precomputed y tables =================
// Round-1/7 HW-verified gather core; indicator scaled by 1/deg (bf16) folds the mean
// into the MFMA. acc accumulates across phases; epilogue adds bf16 root, stores f32.
__device__ __forceinline__ void gather_seg(
    const unsigned short* __restrict__ xs, const int* __restrict__ sorted,
    const int* bnd, unsigned char* stage, unsigned char* segb,
    int lane, int Etot, f32x4* acc) {
    const int b0 = bnd[0];
    const int L  = bnd[16] - b0;
    if (L <= 0) return;                     // empty 16-dst group: nothing to do
    int nchunk = (L + 31) >> 5;
    if (nchunk > 20) nchunk = 20;           // segb capacity; statistically unreachable
    const int tot = nchunk << 5;
    // segment ids; padded slots (i >= L) get id 16 -> match no lane -> contribute 0
    for (int i = lane; i < tot; i += 64) {
        int k = b0 + i;
        int s = 0;
        #pragma unroll
        for (int t = 1; t <= 16; t++) s += (k >= bnd[t]) ? 1 : 0;
        segb[i] = (unsigned char)s;
    }
    const int l15 = lane & 15;
    int deg = bnd[l15 + 1] - bnd[l15];
    const short ivb = (short)f32_to_bf16_rne(1.0f / (float)max(deg, 1));  // mean folded in
    const int jsel = (lane & 7) >> 1;                       // staging row-select
    const int laneoff = ((lane >> 3) << 5) + ((lane & 1) << 4);
    const unsigned int stage_u =
        (unsigned int)(size_t)(__attribute__((address_space(3))) unsigned char*)stage;
    const unsigned int tbA = stage_u + ((lane >> 4) << 11) + ((lane & 15) << 3);
    const unsigned char* xsb = (const unsigned char*)xs;
    // pads re-read this group's LAST edge (L2-hot), not foreign random rows
    const int kmax = min(b0 + L - 1, Etot - 1);
    for (int c = 0; c < nchunk; c++) {
        int kk = min(b0 + (c << 5) + (lane & 31), kmax);
        const int sv = sorted[kk];
        #pragma unroll
        for (int q = 0; q < 8; q++) {                       // 8 x (4 rows x 256B) per chunk
            int srow = __shfl(sv, (q << 2) + jsel, 64);
            const unsigned char* gp = xsb + (((size_t)srow) << 8) + laneoff;
            __builtin_amdgcn_global_load_lds(
                (const __attribute__((address_space(1))) unsigned int*)gp,
                (__attribute__((address_space(3))) unsigned int*)(stage + (q << 10)),
                16, 0, 0);
        }
        const unsigned long long sg =
            *(const unsigned long long*)(segb + (c << 5) + ((lane >> 4) << 3));
        short8 af;
        #pragma unroll
        for (int j = 0; j < 8; j++)
            af[j] = ((int)((sg >> (j << 3)) & 0xFFull) == l15) ? ivb : (short)0;
        asm volatile("s_waitcnt vmcnt(0)" ::: "memory");    // DMA landed in LDS
        unsigned long long blo[8], bhi[8];
        #pragma unroll
        for (int nt = 0; nt < 8; nt++) {
            asm volatile("ds_read_b64_tr_b16 %0, %2\n\t"
                         "ds_read_b64_tr_b16 %1, %2 offset:1024"
                         : "=&v"(blo[nt]), "=&v"(bhi[nt]) : "v"(tbA + (nt << 7)));
        }
        asm volatile("s_waitcnt lgkmcnt(0)" ::: "memory");
        __builtin_amdgcn_sched_barrier(0);                  // rule #18
        #pragma unroll
        for (int nt = 0; nt < 8; nt++) {
            union { unsigned long long u[2]; short8 s; } cv;
            cv.u[0] = blo[nt]; cv.u[1] = bhi[nt];
            acc[nt] = __builtin_amdgcn_mfma_f32_16x16x32_bf16(af, cv.s, acc[nt], 0, 0, 0);
        }
    }
}

__global__ __launch_bounds__(256) void agg_final(
    const unsigned short* __restrict__ yu, const unsigned short* __restrict__ yi,
    const unsigned short* __restrict__ yt,
    const unsigned short* __restrict__ ru, const unsigned short* __restrict__ ri,
    const int* __restrict__ sorted, const int* __restrict__ off,
    float* __restrict__ out, int N, int Etot) {
    __shared__ __align__(1024) unsigned char smem[4][9216];  // 8K stage + 640 segb + 68 bnd
    const int wid = threadIdx.x >> 6;
    const int lane = threadIdx.x & 63;
    const int grp = blockIdx.x * 4 + wid;
    const int Gi = N >> 4;                  // item groups; then user groups (N%16==0)
    if (grp >= 2 * Gi) return;
    unsigned char* stage = smem[wid];
    unsigned char* segb  = smem[wid] + 8192;
    int* bnd = (int*)(smem[wid] + 8192 + 640);
    const int quad = lane >> 4, l15 = lane & 15;

    f32x4 acc[8];
    #pragma unroll
    for (int i = 0; i < 8; i++) acc[i] = (f32x4){0.f, 0.f, 0.f, 0.f};

    float* op; const unsigned short* rt; int g0;
    if (grp < Gi) {                         // ---- item dst-group ----
        g0 = grp << 4;
        if (lane < 17) bnd[lane] = off[g0 + lane];          // rel 0 (buys, src=user)
        gather_seg(yu, sorted, bnd, stage, segb, lane, Etot, acc);
        if (lane < 17) { int idx = 2 * N + g0 + lane; bnd[lane] = (idx <= 3 * N) ? off[idx] : Etot; }
        gather_seg(yt, sorted, bnd, stage, segb, lane, Etot, acc);  // rel 2 (tags)
        op = out + (size_t)N * DIM; rt = ri;
    } else {                                // ---- user dst-group ----
        g0 = (grp - Gi) << 4;
        if (lane < 17) bnd[lane] = off[N + g0 + lane];      // rel 1 (rev, src=item)
        gather_seg(yi, sorted, bnd, stage, segb, lane, Etot, acc);
        op = out; rt = ru;
    }
    // epilogue: out = acc + root(bf16); root rows L2/L3-warm (written by conv_gemm)
    #pragma unroll
    for (int nt = 0; nt < 8; nt++) {
        #pragma unroll
        for (int r = 0; r < 4; r++) {
            size_t idx = (size_t)(g0 + (quad << 2) + r) * DIM + (nt << 4) + l15;
            op[idx] = acc[nt][r] + bf16_to_f32(rt[idx]);
        }
    }
}

extern "C" void kernel_launch(void* const* d_in, const int* in_sizes, int n_in,
                              void* d_out, int out_size, void* d_ws, size_t ws_size,
                              hipStream_t stream) {
    const float* x_user = (const float*)d_in[0];
    const float* x_item = (const float*)d_in[1];
    const float* x_tag  = (const float*)d_in[2];
    const int* ei_buys  = (const int*)d_in[3];
    const int* ei_rev   = (const int*)d_in[4];
    const int* ei_tags  = (const int*)d_in[5];
    const float* Wl_b = (const float*)d_in[6];
    const float* Wr_b = (const float*)d_in[7];
    const float* b_b  = (const float*)d_in[8];
    const float* Wl_r = (const float*)d_in[9];
    const float* Wr_r = (const float*)d_in[10];
    const float* b_r  = (const float*)d_in[11];
    const float* Wl_t = (const float*)d_in[12];
    const float* Wr_t = (const float*)d_in[13];
    const float* b_t  = (const float*)d_in[14];

    const int N  = NNODE;
    const int E0 = in_sizes[3] / 2, E1 = in_sizes[4] / 2, E2 = in_sizes[5] / 2;
    const int n_user = in_sizes[0] / DIM, n_item = in_sizes[1] / DIM, n_tag = in_sizes[2] / DIM;
    const int n3 = 3 * N;

    // workspace layout (bytes), all coexistent, end 121,926,656 <= 146,324,992
    char* w = (char*)d_ws;
    int* off    = (int*)(w + 0);                     // (3N+1)*4
    int* deg    = (int*)(w + 1200128);               // 3N*4
    int* cursor = (int*)(w + 2400256);               // 3N*4
    int* loc    = (int*)(w + 3600384);               // 3N*4
    int* bsum   = (int*)(w + 4800512);               // 294*4
    int* sorted = (int*)(w + 4801792);               // 12,000,000
    unsigned short* pw_item = (unsigned short*)(w + 16801792);   // 98,304
    unsigned short* pw_user = (unsigned short*)(w + 16900096);   // 65,536
    float* bias_item = (float*)(w + 16965632);       // 512
    float* bias_user = (float*)(w + 16966144);       // 512
    unsigned short* yu = (unsigned short*)(w + 16966656);        // 25,600,000
    unsigned short* yi = (unsigned short*)(w + 42566656);        // 25,600,000
    unsigned short* yt = (unsigned short*)(w + 68166656);        //  2,560,000
    unsigned short* ru = (unsigned short*)(w + 70726656);        // 25,600,000
    unsigned short* ri = (unsigned short*)(w + 96326656);        // 25,600,000

    float* out_all = (float*)d_out;                  // [user | item], each N*DIM f32

    int Etot = E0 + E1 + E2;

    hipMemsetAsync(deg, 0, (size_t)n3 * sizeof(int), stream);

    pack_kernel<<<(49152 + 32768 + 2 * DIM + 255) / 256, 256, 0, stream>>>(
        Wl_b, Wr_b, b_b, Wl_r, Wr_r, b_r, Wl_t, Wr_t, b_t,
        pw_item, pw_user, bias_item, bias_user);

    int GU = n_user / 16, GI = n_item / 16, GT = n_tag / 16;
    conv_gemm<<<(GU + GI + GT + 3) / 4, 256, 0, stream>>>(
        x_user, x_item, x_tag, pw_item, pw_user, bias_item, bias_user,
        yu, yi, yt, ru, ri, GU, GI, GT);

    // counting sort: hist -> 3-stage scan -> scatter
    edge_hist<<<2048, 256, 0, stream>>>(ei_buys, ei_rev, ei_tags, E0, E1, E2, deg);

    int nblkA = (n3 + 1023) / 1024;                  // 293
    scan_a<<<nblkA, 1024, 0, stream>>>(deg, loc, bsum, n3);
    scan_b<<<1, 512, 0, stream>>>(bsum, nblkA);
    scan_c<<<(n3 + 1 + 255) / 256, 256, 0, stream>>>(loc, bsum, off, cursor, n3, Etot);

    edge_scatter<<<2048, 256, 0, stream>>>(ei_buys, ei_rev, ei_tags, E0, E1, E2, cursor, sorted);

    // pure gather + scaled-indicator MFMA + root add; item groups then user groups
    int ngrp = 2 * (N / 16);
    agg_final<<<(ngrp + 3) / 4, 256, 0, stream>>>(
        yu, yi, yt, ru, ri, sorted, off, out_all, N, Etot);
}

// Round 9
// 423.136 us; speedup vs baseline: 1.7036x; 1.7036x over previous
//
#include <hip/hip_runtime.h>
#include <hip/hip_bf16.h>
#include <stdint.h>

#define DIM 128
#define NNODE 100000
#define NB 196           // coarse bins per relation (512 dsts each)
#define NBT (3 * NB)     // 588
#define T_TILE 4096      // edges per coarse-scatter tile

typedef __attribute__((ext_vector_type(8))) short short8;
typedef __attribute__((ext_vector_type(4))) float f32x4;

__device__ __forceinline__ unsigned short f32_to_bf16_rne(float f) {
    union { float f; uint32_t u; } v; v.f = f;
    uint32_t u = v.u;
    uint32_t r = u + 0x7FFFu + ((u >> 16) & 1u);
    return (unsigned short)(r >> 16);
}
__device__ __forceinline__ float bf16_to_f32(unsigned short u) {
    union { uint32_t i; float f; } v; v.i = ((uint32_t)u) << 16; return v.f;
}

// ---------------- coarse histogram (LDS pre-aggregated) ----------------
__global__ __launch_bounds__(256) void coarse_hist(
    const int* __restrict__ ei0, const int* __restrict__ ei1, const int* __restrict__ ei2,
    int E0, int E1, int E2, int* __restrict__ ccnt) {
    __shared__ int h[NBT];
    int Etot = E0 + E1 + E2;
    for (int i = threadIdx.x; i < NBT; i += 256) h[i] = 0;
    __syncthreads();
    for (int e = blockIdx.x * blockDim.x + threadIdx.x; e < Etot; e += gridDim.x * blockDim.x) {
        int rel, le; const int* ei; int E;
        if (e < E0)           { rel = 0; le = e;           ei = ei0; E = E0; }
        else if (e < E0 + E1) { rel = 1; le = e - E0;      ei = ei1; E = E1; }
        else                  { rel = 2; le = e - E0 - E1; ei = ei2; E = E2; }
        int d = ei[E + le];
        atomicAdd(&h[rel * NB + (d >> 9)], 1);
    }
    __syncthreads();
    for (int i = threadIdx.x; i < NBT; i += 256) {
        int c = h[i];
        if (c) atomicAdd(&ccnt[i], c);
    }
}

// ---------------- coarse scan: parallel block scan (NBT=588 < 1024) ----------------
__global__ __launch_bounds__(1024) void coarse_scan(const int* __restrict__ ccnt,
                                                    int* __restrict__ bases,
                                                    int* __restrict__ cursor) {
    __shared__ int s[1024];
    int t = threadIdx.x;
    int v = (t < NBT) ? ccnt[t] : 0;
    s[t] = v;
    __syncthreads();
    for (int d = 1; d < 1024; d <<= 1) {
        int x = (t >= d) ? s[t - d] : 0;
        __syncthreads();
        s[t] += x;
        __syncthreads();
    }
    int excl = s[t] - v;   // exclusive prefix
    if (t < NBT) { bases[t] = excl; cursor[t] = excl; }
    if (t == NBT) bases[NBT] = excl;  // total (v==0 past NBT)
}

// ---------------- coarse scatter: tiled, per-tile reserved runs; packed pairs -------
// pair encoding: src (17 bits) | dst_local (9 bits) << 17
__global__ __launch_bounds__(256) void coarse_scatter(
    const int* __restrict__ ei0, const int* __restrict__ ei1, const int* __restrict__ ei2,
    int E0, int E1, int E2, int* __restrict__ cursor, int* __restrict__ pairs) {
    __shared__ int h[NBT], hb[NBT], lc[NBT];
    int Etot = E0 + E1 + E2;
    int ntiles = (Etot + T_TILE - 1) / T_TILE;
    for (int tile = blockIdx.x; tile < ntiles; tile += gridDim.x) {
        int tbase = tile * T_TILE;
        for (int i = threadIdx.x; i < NBT; i += 256) { h[i] = 0; lc[i] = 0; }
        __syncthreads();
        int binreg[16], valreg[16];
        #pragma unroll
        for (int k = 0; k < 16; k++) {
            int e = tbase + k * 256 + threadIdx.x;
            binreg[k] = -1;
            if (e < Etot) {
                int rel, le; const int* ei; int E;
                if (e < E0)           { rel = 0; le = e;           ei = ei0; E = E0; }
                else if (e < E0 + E1) { rel = 1; le = e - E0;      ei = ei1; E = E1; }
                else                  { rel = 2; le = e - E0 - E1; ei = ei2; E = E2; }
                int d = ei[E + le];
                int s = ei[le];
                int bin = rel * NB + (d >> 9);
                binreg[k] = bin;
                valreg[k] = s | ((d & 511) << 17);
                atomicAdd(&h[bin], 1);
            }
        }
        __syncthreads();
        for (int i = threadIdx.x; i < NBT; i += 256) {
            int c = h[i];
            hb[i] = c ? atomicAdd(&cursor[i], c) : 0;
        }
        __syncthreads();
        #pragma unroll
        for (int k = 0; k < 16; k++) {
            if (binreg[k] >= 0) {
                int bin = binreg[k];
                int pos = hb[bin] + atomicAdd(&lc[bin], 1);
                pairs[pos] = valreg[k];
            }
        }
        __syncthreads();
    }
}

// ---------------- fine sort: 1 block per 512-dst bucket; writes off/sorted ----------
__global__ __launch_bounds__(256) void fine_sort(
    const int* __restrict__ bases, const int* __restrict__ pairs,
    int* __restrict__ off, int* __restrict__ sorted, int N) {
    __shared__ int h[512], ho[512], ssum[256];
    int b = blockIdx.x;
    int rel = b / NB, jb = b - rel * NB;
    int ebase = bases[b], ne = bases[b + 1] - ebase;
    int dbase = jb << 9;
    int tid = threadIdx.x;
    for (int i = tid; i < 512; i += 256) h[i] = 0;
    __syncthreads();
    for (int i = tid; i < ne; i += 256) {
        int dl = pairs[ebase + i] >> 17;
        atomicAdd(&h[dl], 1);
    }
    __syncthreads();
    int v0 = h[tid * 2], v1 = h[tid * 2 + 1];
    int tsum = v0 + v1;
    ssum[tid] = tsum;
    __syncthreads();
    for (int s = 1; s < 256; s <<= 1) {
        int t = (tid >= s) ? ssum[tid - s] : 0;
        __syncthreads();
        ssum[tid] += t;
        __syncthreads();
    }
    int excl = ssum[tid] - tsum;
    ho[tid * 2] = excl;
    ho[tid * 2 + 1] = excl + v0;
    __syncthreads();
    for (int i = tid; i < 512; i += 256) {
        int d = dbase + i;
        if (d < N) off[rel * N + d] = ebase + ho[i];
        h[i] = 0;   // becomes cursor
    }
    __syncthreads();
    for (int i = tid; i < ne; i += 256) {
        int p = pairs[ebase + i];
        int dl = p >> 17;
        int pos = ebase + ho[dl] + atomicAdd(&h[dl], 1);
        sorted[pos] = p & 0x1FFFF;
    }
}

// ---------------- pack weights into MFMA B-fragment order (bf16) + biases ----------------
__global__ void pack_kernel(const float* __restrict__ Wl_b, const float* __restrict__ Wr_b,
                            const float* __restrict__ b_b,
                            const float* __restrict__ Wl_r, const float* __restrict__ Wr_r,
                            const float* __restrict__ b_r,
                            const float* __restrict__ Wl_t, const float* __restrict__ Wr_t,
                            const float* __restrict__ b_t,
                            unsigned short* __restrict__ pw_item,
                            unsigned short* __restrict__ pw_user,
                            float* __restrict__ bias_item, float* __restrict__ bias_user) {
    const int NI = 12 * 8 * 64 * 8;   // item slots: [.5Wl_b | .5Wl_t | .5(Wr_b+Wr_t)]
    const int NU = 8 * 8 * 64 * 8;    // user slots: [Wl_r | Wr_r]
    int o = blockIdx.x * blockDim.x + threadIdx.x;
    if (o < NI) {
        int j = o & 7, lane = (o >> 3) & 63, ks = o >> 12;
        int n = ((o >> 9) & 7) * 16 + (lane & 15);
        int k = (ks & 3) * 32 + (lane >> 4) * 8 + j;
        int src = ks >> 2;
        float v;
        if (src == 0)      v = 0.5f * Wl_b[k * DIM + n];
        else if (src == 1) v = 0.5f * Wl_t[k * DIM + n];
        else               v = 0.5f * (Wr_b[k * DIM + n] + Wr_t[k * DIM + n]);
        pw_item[o] = f32_to_bf16_rne(v);
    } else if (o < NI + NU) {
        int oo = o - NI;
        int j = oo & 7, lane = (oo >> 3) & 63, ks = oo >> 12;
        int n = ((oo >> 9) & 7) * 16 + (lane & 15);
        int k = (ks & 3) * 32 + (lane >> 4) * 8 + j;
        float v = ((ks >> 2) == 0) ? Wl_r[k * DIM + n] : Wr_r[k * DIM + n];
        pw_user[oo] = f32_to_bf16_rne(v);
    } else {
        int oo = o - NI - NU;
        if (oo < DIM)            bias_item[oo] = 0.5f * (b_b[oo] + b_t[oo]);
        else if (oo < 2 * DIM)   bias_user[oo - DIM] = b_r[oo - DIM];
    }
}

// ================= conv + pre-GEMM: x(f32) -> y = x@Wl (bf16), r = x@Wr + b (bf16) ====
// Linearity: mean(x[srcs])@W = mean((x@W)[srcs]) — gather tables carry x@W directly,
// so the agg kernel is a pure gather. One wave per 16 rows; wave-private LDS; fragment
// patterns HW-verified (rounds 1/4/7).
__device__ __forceinline__ void cg_product(
    unsigned char* stage, const short8* af,
    const unsigned short* __restrict__ pw, int slot0,
    const float* __restrict__ bias,            // nullptr for y products
    unsigned short* __restrict__ dst, int g0, int lane) {
    const int quad = lane >> 4, l15 = lane & 15;
    f32x4 acc[8];
    #pragma unroll
    for (int i = 0; i < 8; i++) acc[i] = (f32x4){0.f, 0.f, 0.f, 0.f};
    #pragma unroll
    for (int ksl = 0; ksl < 4; ksl++) {
        const unsigned short* wp = pw + ((size_t)(slot0 + ksl) * 8 * 64 + lane) * 8;
        #pragma unroll
        for (int nt = 0; nt < 8; nt++) {
            short8 wfrag = *(const short8*)(wp + (size_t)nt * 64 * 8);
            acc[nt] = __builtin_amdgcn_mfma_f32_16x16x32_bf16(af[ksl], wfrag, acc[nt], 0, 0, 0);
        }
    }
    unsigned short* outb = (unsigned short*)stage;
    #pragma unroll
    for (int nt = 0; nt < 8; nt++) {
        float bv = bias ? bias[nt * 16 + l15] : 0.f;
        #pragma unroll
        for (int r = 0; r < 4; r++) {
            outb[(((quad << 2) + r) << 7) + (nt << 4) + l15] =
                f32_to_bf16_rne(acc[nt][r] + bv);
        }
    }
    unsigned char* mp = (unsigned char*)(dst + ((size_t)g0 << 7));
    #pragma unroll
    for (int s = 0; s < 4; s++) {
        uint4 vv = *(const uint4*)(stage + (s << 10) + (lane << 4));
        *(uint4*)(mp + (s << 10) + (lane << 4)) = vv;
    }
}

__global__ __launch_bounds__(256) void conv_gemm(
    const float* __restrict__ xu, const float* __restrict__ xi, const float* __restrict__ xt,
    const unsigned short* __restrict__ pw_item, const unsigned short* __restrict__ pw_user,
    const float* __restrict__ bias_item, const float* __restrict__ bias_user,
    unsigned short* __restrict__ yu, unsigned short* __restrict__ yi,
    unsigned short* __restrict__ yt,
    unsigned short* __restrict__ ru, unsigned short* __restrict__ ri,
    int GU, int GI, int GT) {
    __shared__ __align__(1024) unsigned char smem[4][4096];
    const int wid = threadIdx.x >> 6;
    const int lane = threadIdx.x & 63;
    const int grp = blockIdx.x * 4 + wid;
    if (grp >= GU + GI + GT) return;
    const float* src; const unsigned short *pwA, *pwB; const float* biasB;
    unsigned short *outA, *outB; int slotA, slotB, g0; bool two;
    if (grp < GU) {
        g0 = grp << 4; src = xu + ((size_t)g0 << 7);
        pwA = pw_item; slotA = 0; outA = yu;                   // yu = x_user @ .5Wl_b
        pwB = pw_user; slotB = 4; outB = ru; biasB = bias_user; two = true;  // r_user
    } else if (grp < GU + GI) {
        g0 = (grp - GU) << 4; src = xi + ((size_t)g0 << 7);
        pwA = pw_user; slotA = 0; outA = yi;                   // yi = x_item @ Wl_r
        pwB = pw_item; slotB = 8; outB = ri; biasB = bias_item; two = true;  // r_item
    } else {
        g0 = (grp - GU - GI) << 4; src = xt + ((size_t)g0 << 7);
        pwA = pw_item; slotA = 4; outA = yt; two = false;      // yt = x_tag @ .5Wl_t
        pwB = nullptr; outB = nullptr; biasB = nullptr; slotB = 0;
    }
    unsigned char* stage = smem[wid];
    // stream 16 rows (8KB f32, coalesced) -> bf16 swizzled LDS tile [16][128]
    #pragma unroll
    for (int s = 0; s < 8; s++) {
        float4 f = *(const float4*)((const unsigned char*)src + (s << 10) + (lane << 4));
        int row = (s << 1) + (lane >> 5);
        unsigned int b = ((unsigned int)row << 8) + ((unsigned int)(lane & 31) << 3);
        b ^= (unsigned int)((row & 15) << 4);
        ushort4 u;
        u.x = f32_to_bf16_rne(f.x); u.y = f32_to_bf16_rne(f.y);
        u.z = f32_to_bf16_rne(f.z); u.w = f32_to_bf16_rne(f.w);
        *(ushort4*)(stage + b) = u;
    }
    // A-fragments (row = lane&15, k = ksl*32 + quad*8 .. +8); same XOR on read
    short8 af[4];
    const int quad = lane >> 4, l15 = lane & 15;
    #pragma unroll
    for (int ksl = 0; ksl < 4; ksl++) {
        unsigned int rb = ((unsigned int)l15 << 8) + (ksl << 6) + (quad << 4);
        rb ^= (unsigned int)(l15 << 4);
        af[ksl] = *(const short8*)(stage + rb);
    }
    cg_product(stage, af, pwA, slotA, nullptr, outA, g0, lane);
    if (two) cg_product(stage, af, pwB, slotB, biasB, outB, g0, lane);
}

// ================= MFMA segment mean over precomputed y tables =================
// Round-1/7 HW-verified gather core; indicator scaled by 1/deg (bf16) folds the mean
// into the MFMA. acc accumulates across phases; epilogue adds bf16 root, stores f32.
__device__ __forceinline__ void gather_seg(
    const unsigned short* __restrict__ xs, const int* __restrict__ sorted,
    const int* bnd, unsigned char* stage, unsigned char* segb,
    int lane, int Etot, f32x4* acc) {
    const int b0 = bnd[0];
    const int L  = bnd[16] - b0;
    if (L <= 0) return;                     // empty 16-dst group: nothing to do
    int nchunk = (L + 31) >> 5;
    if (nchunk > 20) nchunk = 20;           // segb capacity; statistically unreachable
    const int tot = nchunk << 5;
    // segment ids; padded slots (i >= L) get id 16 -> match no lane -> contribute 0
    for (int i = lane; i < tot; i += 64) {
        int k = b0 + i;
        int s = 0;
        #pragma unroll
        for (int t = 1; t <= 16; t++) s += (k >= bnd[t]) ? 1 : 0;
        segb[i] = (unsigned char)s;
    }
    const int l15 = lane & 15;
    int deg = bnd[l15 + 1] - bnd[l15];
    const short ivb = (short)f32_to_bf16_rne(1.0f / (float)max(deg, 1));  // mean folded in
    const int jsel = (lane & 7) >> 1;                       // staging row-select
    const int laneoff = ((lane >> 3) << 5) + ((lane & 1) << 4);
    const unsigned int stage_u =
        (unsigned int)(size_t)(__attribute__((address_space(3))) unsigned char*)stage;
    const unsigned int tbA = stage_u + ((lane >> 4) << 11) + ((lane & 15) << 3);
    const unsigned char* xsb = (const unsigned char*)xs;
    // pads re-read this group's LAST edge (L2-hot), not foreign random rows
    const int kmax = min(b0 + L - 1, Etot - 1);
    for (int c = 0; c < nchunk; c++) {
        int kk = min(b0 + (c << 5) + (lane & 31), kmax);
        const int sv = sorted[kk];
        #pragma unroll
        for (int q = 0; q < 8; q++) {                       // 8 x (4 rows x 256B) per chunk
            int srow = __shfl(sv, (q << 2) + jsel, 64);
            const unsigned char* gp = xsb + (((size_t)srow) << 8) + laneoff;
            __builtin_amdgcn_global_load_lds(
                (const __attribute__((address_space(1))) unsigned int*)gp,
                (__attribute__((address_space(3))) unsigned int*)(stage + (q << 10)),
                16, 0, 0);
        }
        const unsigned long long sg =
            *(const unsigned long long*)(segb + (c << 5) + ((lane >> 4) << 3));
        short8 af;
        #pragma unroll
        for (int j = 0; j < 8; j++)
            af[j] = ((int)((sg >> (j << 3)) & 0xFFull) == l15) ? ivb : (short)0;
        asm volatile("s_waitcnt vmcnt(0)" ::: "memory");    // DMA landed in LDS
        unsigned long long blo[8], bhi[8];
        #pragma unroll
        for (int nt = 0; nt < 8; nt++) {
            asm volatile("ds_read_b64_tr_b16 %0, %2\n\t"
                         "ds_read_b64_tr_b16 %1, %2 offset:1024"
                         : "=&v"(blo[nt]), "=&v"(bhi[nt]) : "v"(tbA + (nt << 7)));
        }
        asm volatile("s_waitcnt lgkmcnt(0)" ::: "memory");
        __builtin_amdgcn_sched_barrier(0);                  // rule #18
        #pragma unroll
        for (int nt = 0; nt < 8; nt++) {
            union { unsigned long long u[2]; short8 s; } cv;
            cv.u[0] = blo[nt]; cv.u[1] = bhi[nt];
            acc[nt] = __builtin_amdgcn_mfma_f32_16x16x32_bf16(af, cv.s, acc[nt], 0, 0, 0);
        }
    }
}

__global__ __launch_bounds__(256) void agg_final(
    const unsigned short* __restrict__ yu, const unsigned short* __restrict__ yi,
    const unsigned short* __restrict__ yt,
    const unsigned short* __restrict__ ru, const unsigned short* __restrict__ ri,
    const int* __restrict__ sorted, const int* __restrict__ off,
    float* __restrict__ out, int N, int Etot) {
    __shared__ __align__(1024) unsigned char smem[4][9216];  // 8K stage + 640 segb + 68 bnd
    const int wid = threadIdx.x >> 6;
    const int lane = threadIdx.x & 63;
    const int grp = blockIdx.x * 4 + wid;
    const int Gi = N >> 4;                  // item groups; then user groups (N%16==0)
    if (grp >= 2 * Gi) return;
    unsigned char* stage = smem[wid];
    unsigned char* segb  = smem[wid] + 8192;
    int* bnd = (int*)(smem[wid] + 8192 + 640);
    const int quad = lane >> 4, l15 = lane & 15;

    f32x4 acc[8];
    #pragma unroll
    for (int i = 0; i < 8; i++) acc[i] = (f32x4){0.f, 0.f, 0.f, 0.f};

    float* op; const unsigned short* rt; int g0;
    if (grp < Gi) {                         // ---- item dst-group ----
        g0 = grp << 4;
        if (lane < 17) bnd[lane] = off[g0 + lane];          // rel 0 (buys, src=user)
        gather_seg(yu, sorted, bnd, stage, segb, lane, Etot, acc);
        if (lane < 17) { int idx = 2 * N + g0 + lane; bnd[lane] = (idx < 3 * N) ? off[idx] : Etot; }
        gather_seg(yt, sorted, bnd, stage, segb, lane, Etot, acc);  // rel 2 (tags)
        op = out + (size_t)N * DIM; rt = ri;
    } else {                                // ---- user dst-group ----
        g0 = (grp - Gi) << 4;
        if (lane < 17) bnd[lane] = off[N + g0 + lane];      // rel 1 (rev, src=item)
        gather_seg(yi, sorted, bnd, stage, segb, lane, Etot, acc);
        op = out; rt = ru;
    }
    // epilogue: out = acc + root(bf16); root rows L2/L3-warm (written by conv_gemm)
    #pragma unroll
    for (int nt = 0; nt < 8; nt++) {
        #pragma unroll
        for (int r = 0; r < 4; r++) {
            size_t idx = (size_t)(g0 + (quad << 2) + r) * DIM + (nt << 4) + l15;
            op[idx] = acc[nt][r] + bf16_to_f32(rt[idx]);
        }
    }
}

extern "C" void kernel_launch(void* const* d_in, const int* in_sizes, int n_in,
                              void* d_out, int out_size, void* d_ws, size_t ws_size,
                              hipStream_t stream) {
    const float* x_user = (const float*)d_in[0];
    const float* x_item = (const float*)d_in[1];
    const float* x_tag  = (const float*)d_in[2];
    const int* ei_buys  = (const int*)d_in[3];
    const int* ei_rev   = (const int*)d_in[4];
    const int* ei_tags  = (const int*)d_in[5];
    const float* Wl_b = (const float*)d_in[6];
    const float* Wr_b = (const float*)d_in[7];
    const float* b_b  = (const float*)d_in[8];
    const float* Wl_r = (const float*)d_in[9];
    const float* Wr_r = (const float*)d_in[10];
    const float* b_r  = (const float*)d_in[11];
    const float* Wl_t = (const float*)d_in[12];
    const float* Wr_t = (const float*)d_in[13];
    const float* b_t  = (const float*)d_in[14];

    const int N  = NNODE;
    const int E0 = in_sizes[3] / 2, E1 = in_sizes[4] / 2, E2 = in_sizes[5] / 2;
    const int n_user = in_sizes[0] / DIM, n_item = in_sizes[1] / DIM, n_tag = in_sizes[2] / DIM;

    // workspace layout (bytes), all coexistent, end 130,332,288 <= 146,324,992
    char* w = (char*)d_ws;
    int* off    = (int*)(w + 0);                     // (3N+1)*4
    int* ccnt   = (int*)(w + 1200128);               // 588*4
    int* bases  = (int*)(w + 1202560);               // 589*4
    int* cursor = (int*)(w + 1204992);               // 588*4
    int* sorted = (int*)(w + 1207424);               // 12,000,000
    int* pairs  = (int*)(w + 13207424);              // 12,000,000
    unsigned short* pw_item = (unsigned short*)(w + 25207424);   // 98,304
    unsigned short* pw_user = (unsigned short*)(w + 25305728);   // 65,536
    float* bias_item = (float*)(w + 25371264);       // 512
    float* bias_user = (float*)(w + 25371776);       // 512
    unsigned short* yu = (unsigned short*)(w + 25372288);        // 25,600,000
    unsigned short* yi = (unsigned short*)(w + 50972288);        // 25,600,000
    unsigned short* yt = (unsigned short*)(w + 76572288);        //  2,560,000
    unsigned short* ru = (unsigned short*)(w + 79132288);        // 25,600,000
    unsigned short* ri = (unsigned short*)(w + 104732288);       // 25,600,000

    float* out_all = (float*)d_out;                  // [user | item], each N*DIM f32

    int Etot = E0 + E1 + E2;

    hipMemsetAsync(ccnt, 0, NBT * sizeof(int), stream);

    pack_kernel<<<(49152 + 32768 + 2 * DIM + 255) / 256, 256, 0, stream>>>(
        Wl_b, Wr_b, b_b, Wl_r, Wr_r, b_r, Wl_t, Wr_t, b_t,
        pw_item, pw_user, bias_item, bias_user);

    int GU = n_user / 16, GI = n_item / 16, GT = n_tag / 16;
    conv_gemm<<<(GU + GI + GT + 3) / 4, 256, 0, stream>>>(
        x_user, x_item, x_tag, pw_item, pw_user, bias_item, bias_user,
        yu, yi, yt, ru, ri, GU, GI, GT);

    coarse_hist<<<512, 256, 0, stream>>>(ei_buys, ei_rev, ei_tags, E0, E1, E2, ccnt);

    coarse_scan<<<1, 1024, 0, stream>>>(ccnt, bases, cursor);

    int ntiles = (Etot + T_TILE - 1) / T_TILE;
    coarse_scatter<<<ntiles, 256, 0, stream>>>(
        ei_buys, ei_rev, ei_tags, E0, E1, E2, cursor, pairs);

    fine_sort<<<NBT, 256, 0, stream>>>(bases, pairs, off, sorted, N);

    // pure gather + scaled-indicator MFMA + root add; item groups then user groups
    int ngrp = 2 * (N / 16);
    agg_final<<<(ngrp + 3) / 4, 256, 0, stream>>>(
        yu, yi, yt, ru, ri, sorted, off, out_all, N, Etot);
}

// Round 10
// 416.181 us; speedup vs baseline: 1.7321x; 1.0167x over previous
//
#include <hip/hip_runtime.h>
#include <hip/hip_bf16.h>
#include <stdint.h>

#define DIM 128
#define NNODE 100000
#define NB 196           // coarse bins per relation (512 dsts each)
#define NBT (3 * NB)     // 588
#define T_TILE 4096      // edges per coarse-scatter tile
#define NHIST 512        // hist blocks fused at the front of prep_kernel

typedef __attribute__((ext_vector_type(8))) short short8;
typedef __attribute__((ext_vector_type(4))) float f32x4;

__device__ __forceinline__ unsigned short f32_to_bf16_rne(float f) {
    union { float f; uint32_t u; } v; v.f = f;
    uint32_t u = v.u;
    uint32_t r = u + 0x7FFFu + ((u >> 16) & 1u);
    return (unsigned short)(r >> 16);
}
__device__ __forceinline__ float bf16_to_f32(unsigned short u) {
    union { uint32_t i; float f; } v; v.i = ((uint32_t)u) << 16; return v.f;
}

// ---------------- coarse scan: parallel block scan (NBT=588 < 1024) ----------------
__global__ __launch_bounds__(1024) void coarse_scan(const int* __restrict__ ccnt,
                                                    int* __restrict__ bases,
                                                    int* __restrict__ cursor) {
    __shared__ int s[1024];
    int t = threadIdx.x;
    int v = (t < NBT) ? ccnt[t] : 0;
    s[t] = v;
    __syncthreads();
    for (int d = 1; d < 1024; d <<= 1) {
        int x = (t >= d) ? s[t - d] : 0;
        __syncthreads();
        s[t] += x;
        __syncthreads();
    }
    int excl = s[t] - v;   // exclusive prefix
    if (t < NBT) { bases[t] = excl; cursor[t] = excl; }
    if (t == NBT) bases[NBT] = excl;  // total (v==0 past NBT)
}

// ---------------- coarse scatter: tiled, per-tile reserved runs; packed pairs -------
// pair encoding: src (17 bits) | dst_local (9 bits) << 17
__global__ __launch_bounds__(256) void coarse_scatter(
    const int* __restrict__ ei0, const int* __restrict__ ei1, const int* __restrict__ ei2,
    int E0, int E1, int E2, int* __restrict__ cursor, int* __restrict__ pairs) {
    __shared__ int h[NBT], hb[NBT], lc[NBT];
    int Etot = E0 + E1 + E2;
    int ntiles = (Etot + T_TILE - 1) / T_TILE;
    for (int tile = blockIdx.x; tile < ntiles; tile += gridDim.x) {
        int tbase = tile * T_TILE;
        for (int i = threadIdx.x; i < NBT; i += 256) { h[i] = 0; lc[i] = 0; }
        __syncthreads();
        int binreg[16], valreg[16];
        #pragma unroll
        for (int k = 0; k < 16; k++) {
            int e = tbase + k * 256 + threadIdx.x;
            binreg[k] = -1;
            if (e < Etot) {
                int rel, le; const int* ei; int E;
                if (e < E0)           { rel = 0; le = e;           ei = ei0; E = E0; }
                else if (e < E0 + E1) { rel = 1; le = e - E0;      ei = ei1; E = E1; }
                else                  { rel = 2; le = e - E0 - E1; ei = ei2; E = E2; }
                int d = ei[E + le];
                int s = ei[le];
                int bin = rel * NB + (d >> 9);
                binreg[k] = bin;
                valreg[k] = s | ((d & 511) << 17);
                atomicAdd(&h[bin], 1);
            }
        }
        __syncthreads();
        for (int i = threadIdx.x; i < NBT; i += 256) {
            int c = h[i];
            hb[i] = c ? atomicAdd(&cursor[i], c) : 0;
        }
        __syncthreads();
        #pragma unroll
        for (int k = 0; k < 16; k++) {
            if (binreg[k] >= 0) {
                int bin = binreg[k];
                int pos = hb[bin] + atomicAdd(&lc[bin], 1);
                pairs[pos] = valreg[k];
            }
        }
        __syncthreads();
    }
}

// ---------------- fine sort: 1 block per 512-dst bucket; writes off/sorted ----------
__global__ __launch_bounds__(256) void fine_sort(
    const int* __restrict__ bases, const int* __restrict__ pairs,
    int* __restrict__ off, int* __restrict__ sorted, int N) {
    __shared__ int h[512], ho[512], ssum[256];
    int b = blockIdx.x;
    int rel = b / NB, jb = b - rel * NB;
    int ebase = bases[b], ne = bases[b + 1] - ebase;
    int dbase = jb << 9;
    int tid = threadIdx.x;
    for (int i = tid; i < 512; i += 256) h[i] = 0;
    __syncthreads();
    for (int i = tid; i < ne; i += 256) {
        int dl = pairs[ebase + i] >> 17;
        atomicAdd(&h[dl], 1);
    }
    __syncthreads();
    int v0 = h[tid * 2], v1 = h[tid * 2 + 1];
    int tsum = v0 + v1;
    ssum[tid] = tsum;
    __syncthreads();
    for (int s = 1; s < 256; s <<= 1) {
        int t = (tid >= s) ? ssum[tid - s] : 0;
        __syncthreads();
        ssum[tid] += t;
        __syncthreads();
    }
    int excl = ssum[tid] - tsum;
    ho[tid * 2] = excl;
    ho[tid * 2 + 1] = excl + v0;
    __syncthreads();
    for (int i = tid; i < 512; i += 256) {
        int d = dbase + i;
        if (d < N) off[rel * N + d] = ebase + ho[i];
        h[i] = 0;   // becomes cursor
    }
    __syncthreads();
    for (int i = tid; i < ne; i += 256) {
        int p = pairs[ebase + i];
        int dl = p >> 17;
        int pos = ebase + ho[dl] + atomicAdd(&h[dl], 1);
        sorted[pos] = p & 0x1FFFF;
    }
}

// -------- pack weights into MFMA B-fragment order (bf16) + biases; zeroes ccnt ------
__global__ void pack_kernel(const float* __restrict__ Wl_b, const float* __restrict__ Wr_b,
                            const float* __restrict__ b_b,
                            const float* __restrict__ Wl_r, const float* __restrict__ Wr_r,
                            const float* __restrict__ b_r,
                            const float* __restrict__ Wl_t, const float* __restrict__ Wr_t,
                            const float* __restrict__ b_t,
                            unsigned short* __restrict__ pw_item,
                            unsigned short* __restrict__ pw_user,
                            float* __restrict__ bias_item, float* __restrict__ bias_user,
                            int* __restrict__ ccnt) {
    const int NI = 12 * 8 * 64 * 8;   // item slots: [.5Wl_b | .5Wl_t | .5(Wr_b+Wr_t)]
    const int NU = 8 * 8 * 64 * 8;    // user slots: [Wl_r | Wr_r]
    int o = blockIdx.x * blockDim.x + threadIdx.x;
    if (o < NBT) ccnt[o] = 0;         // replaces the hipMemsetAsync launch
    if (o < NI) {
        int j = o & 7, lane = (o >> 3) & 63, ks = o >> 12;
        int n = ((o >> 9) & 7) * 16 + (lane & 15);
        int k = (ks & 3) * 32 + (lane >> 4) * 8 + j;
        int src = ks >> 2;
        float v;
        if (src == 0)      v = 0.5f * Wl_b[k * DIM + n];
        else if (src == 1) v = 0.5f * Wl_t[k * DIM + n];
        else               v = 0.5f * (Wr_b[k * DIM + n] + Wr_t[k * DIM + n]);
        pw_item[o] = f32_to_bf16_rne(v);
    } else if (o < NI + NU) {
        int oo = o - NI;
        int j = oo & 7, lane = (oo >> 3) & 63, ks = oo >> 12;
        int n = ((oo >> 9) & 7) * 16 + (lane & 15);
        int k = (ks & 3) * 32 + (lane >> 4) * 8 + j;
        float v = ((ks >> 2) == 0) ? Wl_r[k * DIM + n] : Wr_r[k * DIM + n];
        pw_user[oo] = f32_to_bf16_rne(v);
    } else {
        int oo = o - NI - NU;
        if (oo < DIM)            bias_item[oo] = 0.5f * (b_b[oo] + b_t[oo]);
        else if (oo < 2 * DIM)   bias_user[oo - DIM] = b_r[oo - DIM];
    }
}

// ================= prep: fused {coarse_hist | conv+pre-GEMM} by block range =========
// Hist blocks first (overlap conv's stream). Conv: A-frags read DIRECT from global f32
// (R4 gemm_kernel's verified pattern) and converted in-register — no LDS input staging.
// LDS used only for the output bf16 pack (wave-private, first use after MFMA).
__device__ __forceinline__ void cg_product(
    unsigned char* stage, const short8* af,
    const unsigned short* __restrict__ pw, int slot0,
    const float* __restrict__ bias,            // nullptr for y products
    unsigned short* __restrict__ dst, int g0, int lane) {
    const int quad = lane >> 4, l15 = lane & 15;
    f32x4 acc[8];
    #pragma unroll
    for (int i = 0; i < 8; i++) acc[i] = (f32x4){0.f, 0.f, 0.f, 0.f};
    #pragma unroll
    for (int ksl = 0; ksl < 4; ksl++) {
        const unsigned short* wp = pw + ((size_t)(slot0 + ksl) * 8 * 64 + lane) * 8;
        #pragma unroll
        for (int nt = 0; nt < 8; nt++) {
            short8 wfrag = *(const short8*)(wp + (size_t)nt * 64 * 8);
            acc[nt] = __builtin_amdgcn_mfma_f32_16x16x32_bf16(af[ksl], wfrag, acc[nt], 0, 0, 0);
        }
    }
    unsigned short* outb = (unsigned short*)stage;
    #pragma unroll
    for (int nt = 0; nt < 8; nt++) {
        float bv = bias ? bias[nt * 16 + l15] : 0.f;
        #pragma unroll
        for (int r = 0; r < 4; r++) {
            outb[(((quad << 2) + r) << 7) + (nt << 4) + l15] =
                f32_to_bf16_rne(acc[nt][r] + bv);
        }
    }
    unsigned char* mp = (unsigned char*)(dst + ((size_t)g0 << 7));
    #pragma unroll
    for (int s = 0; s < 4; s++) {
        uint4 vv = *(const uint4*)(stage + (s << 10) + (lane << 4));
        *(uint4*)(mp + (s << 10) + (lane << 4)) = vv;
    }
}

__global__ __launch_bounds__(256) void prep_kernel(
    const float* __restrict__ xu, const float* __restrict__ xi, const float* __restrict__ xt,
    const unsigned short* __restrict__ pw_item, const unsigned short* __restrict__ pw_user,
    const float* __restrict__ bias_item, const float* __restrict__ bias_user,
    unsigned short* __restrict__ yu, unsigned short* __restrict__ yi,
    unsigned short* __restrict__ yt,
    unsigned short* __restrict__ ru, unsigned short* __restrict__ ri,
    int GU, int GI, int GT,
    const int* __restrict__ ei0, const int* __restrict__ ei1, const int* __restrict__ ei2,
    int E0, int E1, int E2, int* __restrict__ ccnt) {
    __shared__ __align__(1024) unsigned char smem[16384];
    if (blockIdx.x < NHIST) {
        // ---- coarse histogram (R9-verified body; grid-strided over NHIST blocks) ----
        int* h = (int*)smem;
        int Etot = E0 + E1 + E2;
        for (int i = threadIdx.x; i < NBT; i += 256) h[i] = 0;
        __syncthreads();
        for (int e = blockIdx.x * 256 + threadIdx.x; e < Etot; e += NHIST * 256) {
            int rel, le; const int* ei; int E;
            if (e < E0)           { rel = 0; le = e;           ei = ei0; E = E0; }
            else if (e < E0 + E1) { rel = 1; le = e - E0;      ei = ei1; E = E1; }
            else                  { rel = 2; le = e - E0 - E1; ei = ei2; E = E2; }
            int d = ei[E + le];
            atomicAdd(&h[rel * NB + (d >> 9)], 1);
        }
        __syncthreads();
        for (int i = threadIdx.x; i < NBT; i += 256) {
            int c = h[i];
            if (c) atomicAdd(&ccnt[i], c);
        }
        return;
    }
    // ---- conv + pre-GEMM ----
    const int wid = threadIdx.x >> 6;
    const int lane = threadIdx.x & 63;
    const int grp = (blockIdx.x - NHIST) * 4 + wid;
    if (grp >= GU + GI + GT) return;
    const float* src; const unsigned short *pwA, *pwB; const float* biasB;
    unsigned short *outA, *outB; int slotA, slotB, g0; bool two;
    if (grp < GU) {
        g0 = grp << 4; src = xu + ((size_t)g0 << 7);
        pwA = pw_item; slotA = 0; outA = yu;                   // yu = x_user @ .5Wl_b
        pwB = pw_user; slotB = 4; outB = ru; biasB = bias_user; two = true;  // r_user
    } else if (grp < GU + GI) {
        g0 = (grp - GU) << 4; src = xi + ((size_t)g0 << 7);
        pwA = pw_user; slotA = 0; outA = yi;                   // yi = x_item @ Wl_r
        pwB = pw_item; slotB = 8; outB = ri; biasB = bias_item; two = true;  // r_item
    } else {
        g0 = (grp - GU - GI) << 4; src = xt + ((size_t)g0 << 7);
        pwA = pw_item; slotA = 4; outA = yt; two = false;      // yt = x_tag @ .5Wl_t
        pwB = nullptr; outB = nullptr; biasB = nullptr; slotB = 0;
    }
    unsigned char* stage = smem + wid * 4096;
    // A-frags direct from global f32: row = g0+l15, k = ksl*32 + quad*8 .. +8
    const int quad = lane >> 4, l15 = lane & 15;
    const float* rowp = src + (size_t)l15 * DIM;
    short8 af[4];
    #pragma unroll
    for (int ksl = 0; ksl < 4; ksl++) {
        const float* p = rowp + ksl * 32 + quad * 8;
        float4 a = *(const float4*)p;
        float4 b = *(const float4*)(p + 4);
        short8 f;
        f[0] = (short)f32_to_bf16_rne(a.x); f[1] = (short)f32_to_bf16_rne(a.y);
        f[2] = (short)f32_to_bf16_rne(a.z); f[3] = (short)f32_to_bf16_rne(a.w);
        f[4] = (short)f32_to_bf16_rne(b.x); f[5] = (short)f32_to_bf16_rne(b.y);
        f[6] = (short)f32_to_bf16_rne(b.z); f[7] = (short)f32_to_bf16_rne(b.w);
        af[ksl] = f;
    }
    cg_product(stage, af, pwA, slotA, nullptr, outA, g0, lane);
    if (two) cg_product(stage, af, pwB, slotB, biasB, outB, g0, lane);
}

// ================= MFMA segment mean over precomputed y tables =================
// Round-1/7 HW-verified gather core; indicator scaled by 1/deg (bf16) folds the mean
// into the MFMA. acc accumulates across phases; epilogue adds bf16 root, stores f32.
__device__ __forceinline__ void gather_seg(
    const unsigned short* __restrict__ xs, const int* __restrict__ sorted,
    const int* bnd, unsigned char* stage, unsigned char* segb,
    int lane, int Etot, f32x4* acc) {
    const int b0 = bnd[0];
    const int L  = bnd[16] - b0;
    if (L <= 0) return;                     // empty 16-dst group: nothing to do
    int nchunk = (L + 31) >> 5;
    if (nchunk > 20) nchunk = 20;           // segb capacity; statistically unreachable
    const int tot = nchunk << 5;
    // segment ids; padded slots (i >= L) get id 16 -> match no lane -> contribute 0
    for (int i = lane; i < tot; i += 64) {
        int k = b0 + i;
        int s = 0;
        #pragma unroll
        for (int t = 1; t <= 16; t++) s += (k >= bnd[t]) ? 1 : 0;
        segb[i] = (unsigned char)s;
    }
    const int l15 = lane & 15;
    int deg = bnd[l15 + 1] - bnd[l15];
    const short ivb = (short)f32_to_bf16_rne(1.0f / (float)max(deg, 1));  // mean folded in
    const int jsel = (lane & 7) >> 1;                       // staging row-select
    const int laneoff = ((lane >> 3) << 5) + ((lane & 1) << 4);
    const unsigned int stage_u =
        (unsigned int)(size_t)(__attribute__((address_space(3))) unsigned char*)stage;
    const unsigned int tbA = stage_u + ((lane >> 4) << 11) + ((lane & 15) << 3);
    const unsigned char* xsb = (const unsigned char*)xs;
    // pads re-read this group's LAST edge (L2-hot), not foreign random rows
    const int kmax = min(b0 + L - 1, Etot - 1);
    for (int c = 0; c < nchunk; c++) {
        int kk = min(b0 + (c << 5) + (lane & 31), kmax);
        const int sv = sorted[kk];
        #pragma unroll
        for (int q = 0; q < 8; q++) {                       // 8 x (4 rows x 256B) per chunk
            int srow = __shfl(sv, (q << 2) + jsel, 64);
            const unsigned char* gp = xsb + (((size_t)srow) << 8) + laneoff;
            __builtin_amdgcn_global_load_lds(
                (const __attribute__((address_space(1))) unsigned int*)gp,
                (__attribute__((address_space(3))) unsigned int*)(stage + (q << 10)),
                16, 0, 0);
        }
        const unsigned long long sg =
            *(const unsigned long long*)(segb + (c << 5) + ((lane >> 4) << 3));
        short8 af;
        #pragma unroll
        for (int j = 0; j < 8; j++)
            af[j] = ((int)((sg >> (j << 3)) & 0xFFull) == l15) ? ivb : (short)0;
        asm volatile("s_waitcnt vmcnt(0)" ::: "memory");    // DMA landed in LDS
        unsigned long long blo[8], bhi[8];
        #pragma unroll
        for (int nt = 0; nt < 8; nt++) {
            asm volatile("ds_read_b64_tr_b16 %0, %2\n\t"
                         "ds_read_b64_tr_b16 %1, %2 offset:1024"
                         : "=&v"(blo[nt]), "=&v"(bhi[nt]) : "v"(tbA + (nt << 7)));
        }
        asm volatile("s_waitcnt lgkmcnt(0)" ::: "memory");
        __builtin_amdgcn_sched_barrier(0);                  // rule #18
        #pragma unroll
        for (int nt = 0; nt < 8; nt++) {
            union { unsigned long long u[2]; short8 s; } cv;
            cv.u[0] = blo[nt]; cv.u[1] = bhi[nt];
            acc[nt] = __builtin_amdgcn_mfma_f32_16x16x32_bf16(af, cv.s, acc[nt], 0, 0, 0);
        }
    }
}

__global__ __launch_bounds__(256) void agg_final(
    const unsigned short* __restrict__ yu, const unsigned short* __restrict__ yi,
    const unsigned short* __restrict__ yt,
    const unsigned short* __restrict__ ru, const unsigned short* __restrict__ ri,
    const int* __restrict__ sorted, const int* __restrict__ off,
    float* __restrict__ out, int N, int Etot) {
    __shared__ __align__(1024) unsigned char smem[4][9216];  // 8K stage + 640 segb + 68 bnd
    const int wid = threadIdx.x >> 6;
    const int lane = threadIdx.x & 63;
    const int grp = blockIdx.x * 4 + wid;
    const int Gi = N >> 4;                  // item groups; then user groups (N%16==0)
    if (grp >= 2 * Gi) return;
    unsigned char* stage = smem[wid];
    unsigned char* segb  = smem[wid] + 8192;
    int* bnd = (int*)(smem[wid] + 8192 + 640);
    const int quad = lane >> 4, l15 = lane & 15;

    f32x4 acc[8];
    #pragma unroll
    for (int i = 0; i < 8; i++) acc[i] = (f32x4){0.f, 0.f, 0.f, 0.f};

    float* op; const unsigned short* rt; int g0;
    if (grp < Gi) {                         // ---- item dst-group ----
        g0 = grp << 4;
        if (lane < 17) bnd[lane] = off[g0 + lane];          // rel 0 (buys, src=user)
        gather_seg(yu, sorted, bnd, stage, segb, lane, Etot, acc);
        if (lane < 17) { int idx = 2 * N + g0 + lane; bnd[lane] = (idx < 3 * N) ? off[idx] : Etot; }
        gather_seg(yt, sorted, bnd, stage, segb, lane, Etot, acc);  // rel 2 (tags)
        op = out + (size_t)N * DIM; rt = ri;
    } else {                                // ---- user dst-group ----
        g0 = (grp - Gi) << 4;
        if (lane < 17) bnd[lane] = off[N + g0 + lane];      // rel 1 (rev, src=item)
        gather_seg(yi, sorted, bnd, stage, segb, lane, Etot, acc);
        op = out; rt = ru;
    }
    // epilogue: out = acc + root(bf16); root rows L2/L3-warm (written by prep_kernel)
    #pragma unroll
    for (int nt = 0; nt < 8; nt++) {
        #pragma unroll
        for (int r = 0; r < 4; r++) {
            size_t idx = (size_t)(g0 + (quad << 2) + r) * DIM + (nt << 4) + l15;
            op[idx] = acc[nt][r] + bf16_to_f32(rt[idx]);
        }
    }
}

extern "C" void kernel_launch(void* const* d_in, const int* in_sizes, int n_in,
                              void* d_out, int out_size, void* d_ws, size_t ws_size,
                              hipStream_t stream) {
    const float* x_user = (const float*)d_in[0];
    const float* x_item = (const float*)d_in[1];
    const float* x_tag  = (const float*)d_in[2];
    const int* ei_buys  = (const int*)d_in[3];
    const int* ei_rev   = (const int*)d_in[4];
    const int* ei_tags  = (const int*)d_in[5];
    const float* Wl_b = (const float*)d_in[6];
    const float* Wr_b = (const float*)d_in[7];
    const float* b_b  = (const float*)d_in[8];
    const float* Wl_r = (const float*)d_in[9];
    const float* Wr_r = (const float*)d_in[10];
    const float* b_r  = (const float*)d_in[11];
    const float* Wl_t = (const float*)d_in[12];
    const float* Wr_t = (const float*)d_in[13];
    const float* b_t  = (const float*)d_in[14];

    const int N  = NNODE;
    const int E0 = in_sizes[3] / 2, E1 = in_sizes[4] / 2, E2 = in_sizes[5] / 2;
    const int n_user = in_sizes[0] / DIM, n_item = in_sizes[1] / DIM, n_tag = in_sizes[2] / DIM;

    // workspace layout (bytes), all coexistent, end 130,332,288 <= 146,324,992
    char* w = (char*)d_ws;
    int* off    = (int*)(w + 0);                     // (3N+1)*4
    int* ccnt   = (int*)(w + 1200128);               // 588*4
    int* bases  = (int*)(w + 1202560);               // 589*4
    int* cursor = (int*)(w + 1204992);               // 588*4
    int* sorted = (int*)(w + 1207424);               // 12,000,000
    int* pairs  = (int*)(w + 13207424);              // 12,000,000
    unsigned short* pw_item = (unsigned short*)(w + 25207424);   // 98,304
    unsigned short* pw_user = (unsigned short*)(w + 25305728);   // 65,536
    float* bias_item = (float*)(w + 25371264);       // 512
    float* bias_user = (float*)(w + 25371776);       // 512
    unsigned short* yu = (unsigned short*)(w + 25372288);        // 25,600,000
    unsigned short* yi = (unsigned short*)(w + 50972288);        // 25,600,000
    unsigned short* yt = (unsigned short*)(w + 76572288);        //  2,560,000
    unsigned short* ru = (unsigned short*)(w + 79132288);        // 25,600,000
    unsigned short* ri = (unsigned short*)(w + 104732288);       // 25,600,000

    float* out_all = (float*)d_out;                  // [user | item], each N*DIM f32

    int Etot = E0 + E1 + E2;

    // pack weights (+ ccnt zeroing folded in)
    pack_kernel<<<(49152 + 32768 + 2 * DIM + 255) / 256, 256, 0, stream>>>(
        Wl_b, Wr_b, b_b, Wl_r, Wr_r, b_r, Wl_t, Wr_t, b_t,
        pw_item, pw_user, bias_item, bias_user, ccnt);

    // fused {hist | conv+pre-GEMM}: hist blocks first so they overlap conv
    int GU = n_user / 16, GI = n_item / 16, GT = n_tag / 16;
    int conv_blocks = (GU + GI + GT + 3) / 4;
    prep_kernel<<<NHIST + conv_blocks, 256, 0, stream>>>(
        x_user, x_item, x_tag, pw_item, pw_user, bias_item, bias_user,
        yu, yi, yt, ru, ri, GU, GI, GT,
        ei_buys, ei_rev, ei_tags, E0, E1, E2, ccnt);

    coarse_scan<<<1, 1024, 0, stream>>>(ccnt, bases, cursor);

    int ntiles = (Etot + T_TILE - 1) / T_TILE;
    coarse_scatter<<<ntiles, 256, 0, stream>>>(
        ei_buys, ei_rev, ei_tags, E0, E1, E2, cursor, pairs);

    fine_sort<<<NBT, 256, 0, stream>>>(bases, pairs, off, sorted, N);

    // pure gather + scaled-indicator MFMA + root add; item groups then user groups
    int ngrp = 2 * (N / 16);
    agg_final<<<(ngrp + 3) / 4, 256, 0, stream>>>(
        yu, yi, yt, ru, ri, sorted, off, out_all, N, Etot);
}